// Round 6
// baseline (194.116 us; speedup 1.0000x reference)
//
#include <hip/hip_runtime.h>

// RNN scan: h_{t+1} = relu(W_hh @ h_t + x_t * w_x), out = W_hy @ h_T
// B=8192, T=512, H=64.
// Round 6 (on round-5's 2-wave M-split):
//   - own-half bypass: wave wv's own frags (k-blocks 2wv,2wv+1) stay in regs;
//     only the partner half crosses LDS (write 32B/lane -> read 32B/lane).
//   - LDS latency hidden: partner reads issued right after barrier; next
//     step's first 2 MFMAs use register frags, waits auto-inserted at use.
//   - chain split: own-chain (C-in = x*wx) || partner-chain (C-in = 0),
//     merged with v_pk_add -> exposed dep depth 2, not 4.
// Layouts (verified rounds 1-5):
//   A 32x32x16: row=lane&31, k=8*(lane>>5)+e
//   B: col=lane&31, k=8*(lane>>5)+e
//   C: col=lane&31, row=(reg&3)+8*(reg>>2)+4*(lane>>5)
//   permlane32_swap(X,Y): X'={self X|partner Y}, Y'={partner X|self Y}

typedef __bf16 bf16x8 __attribute__((ext_vector_type(8)));
typedef float f32x16 __attribute__((ext_vector_type(16)));
typedef unsigned int u32x4 __attribute__((ext_vector_type(4)));

#define RNN_B 8192
#define RNN_T 512
#define RNN_H 64

__device__ __forceinline__ unsigned pk2_relu(float a, float b) {
  float ra = fmaxf(a, 0.0f), rb = fmaxf(b, 0.0f);
  unsigned short ua = __builtin_bit_cast(unsigned short, (__bf16)ra);
  unsigned short ub = __builtin_bit_cast(unsigned short, (__bf16)rb);
  return (unsigned)ua | ((unsigned)ub << 16);
}

__global__ __launch_bounds__(128, 1) void rnn_scan_kernel(
    const float* __restrict__ x,
    const float* __restrict__ Wxh,
    const float* __restrict__ Whh,
    const float* __restrict__ Why,
    float* __restrict__ out)
{
  const int tid  = threadIdx.x;
  const int wv   = tid >> 6;      // owns C rows [32*wv, 32*wv+32)
  const int pv   = 1 - wv;        // partner wave
  const int lane = tid & 63;
  const int col  = lane & 31;
  const int sel  = lane >> 5;
  const int b0   = blockIdx.x * 32;

  // [buf][srcwave][word][lane]: srcwave w word u holds frag m = 2*w + u
  __shared__ u32x4 xch[2][2][2][64];          // 8 KiB
  __shared__ float partial[2][32];

  // ---- A fragments: this wave's 32 rows of W_hh, k-blocks m=0..3 ----
  bf16x8 A[4];
#pragma unroll
  for (int m = 0; m < 4; ++m) {
    const float* wp = Whh + (32 * wv + col) * RNN_H + 16 * m + 8 * sel;
    float4 w0 = *(const float4*)(wp);
    float4 w1 = *(const float4*)(wp + 4);
    bf16x8 f;
    f[0] = (__bf16)w0.x; f[1] = (__bf16)w0.y; f[2] = (__bf16)w0.z; f[3] = (__bf16)w0.w;
    f[4] = (__bf16)w1.x; f[5] = (__bf16)w1.y; f[6] = (__bf16)w1.z; f[7] = (__bf16)w1.w;
    A[m] = f;
  }

  // ---- w_x per accumulator slot (this wave's rows) ----
  f32x16 wxv;
#pragma unroll
  for (int r = 0; r < 16; ++r)
    wxv[r] = Wxh[32 * wv + (r & 3) + 8 * (r >> 2) + 4 * sel];

  const float* xrow = x + (size_t)(b0 + col) * RNN_T;
  float4 xc0 = *(const float4*)(xrow);
  float4 xc1 = *(const float4*)(xrow + 4);

  f32x16 zf = {};
  f32x16 acc = zf;                 // merged pre-relu h half (this wave's rows)
  u32x4 own0 = {}, own1 = {};      // own packed frags (k-blocks 2wv, 2wv+1)
  u32x4 p0, p1;                    // partner frags (k-blocks 2pv, 2pv+1)

  // prologue = virtual step -1: publish h_0 = 0, issue first partner reads
  xch[0][wv][0][lane] = own0;
  xch[0][wv][1][lane] = own1;
  asm volatile("s_waitcnt lgkmcnt(0)\n\ts_barrier" ::: "memory");
  p0 = xch[0][pv][0][lane];
  p1 = xch[0][pv][1][lane];

  for (int tb = 0; tb < RNN_T; tb += 8) {
    const int tn = (tb + 8 < RNN_T) ? tb + 8 : tb;
    float4 xn0 = *(const float4*)(xrow + tn);
    float4 xn1 = *(const float4*)(xrow + tn + 4);
    const float xs[8] = {xc0.x, xc0.y, xc0.z, xc0.w, xc1.x, xc1.y, xc1.z, xc1.w};
#pragma unroll
    for (int j = 0; j < 8; ++j) {
      const float xv = xs[j];
      // own chain: C-in = f32-exact x-term; frags already in regs (no wait)
      f32x16 aO = wxv * xv;
      aO = __builtin_amdgcn_mfma_f32_32x32x16_bf16(A[2 * wv],     __builtin_bit_cast(bf16x8, own0), aO, 0, 0, 0);
      aO = __builtin_amdgcn_mfma_f32_32x32x16_bf16(A[2 * wv + 1], __builtin_bit_cast(bf16x8, own1), aO, 0, 0, 0);
      // partner chain: compiler inserts lgkm wait for p0/p1 here (hidden
      // under the two own-MFMAs above)
      f32x16 aP;
      aP = __builtin_amdgcn_mfma_f32_32x32x16_bf16(A[2 * pv],     __builtin_bit_cast(bf16x8, p0), zf, 0, 0, 0);
      aP = __builtin_amdgcn_mfma_f32_32x32x16_bf16(A[2 * pv + 1], __builtin_bit_cast(bf16x8, p1), aP, 0, 0, 0);
      acc = aO + aP;                       // v_pk_add_f32 x8

      // pack own half: rows [32wv,32wv+16) -> own0, [32wv+16,32wv+32) -> own1
      {
        unsigned X0 = pk2_relu(acc[0], acc[1]);
        unsigned X1 = pk2_relu(acc[2], acc[3]);
        unsigned Y0 = pk2_relu(acc[4], acc[5]);
        unsigned Y1 = pk2_relu(acc[6], acc[7]);
        asm("v_permlane32_swap_b32 %0, %1" : "+v"(X0), "+v"(Y0));
        asm("v_permlane32_swap_b32 %0, %1" : "+v"(X1), "+v"(Y1));
        own0[0] = X0; own0[1] = X1; own0[2] = Y0; own0[3] = Y1;
      }
      {
        unsigned X0 = pk2_relu(acc[8],  acc[9]);
        unsigned X1 = pk2_relu(acc[10], acc[11]);
        unsigned Y0 = pk2_relu(acc[12], acc[13]);
        unsigned Y1 = pk2_relu(acc[14], acc[15]);
        asm("v_permlane32_swap_b32 %0, %1" : "+v"(X0), "+v"(Y0));
        asm("v_permlane32_swap_b32 %0, %1" : "+v"(X1), "+v"(Y1));
        own1[0] = X0; own1[1] = X1; own1[2] = Y0; own1[3] = Y1;
      }

      // publish h_{t+1} (buf (t+1)&1), then issue next partner reads
      const int q = (j & 1) ^ 1;
      xch[q][wv][0][lane] = own0;
      xch[q][wv][1][lane] = own1;
      asm volatile("s_waitcnt lgkmcnt(0)\n\ts_barrier" ::: "memory");
      p0 = xch[q][pv][0][lane];
      p1 = xch[q][pv][1][lane];
    }
    xc0 = xn0; xc1 = xn1;
  }

  // ---- epilogue: out[b] = sum over this wave's rows, then cross-wave ----
  float pw = 0.0f;
#pragma unroll
  for (int r = 0; r < 16; ++r) {
    const int row = 32 * wv + (r & 3) + 8 * (r >> 2) + 4 * sel;
    pw += Why[row] * fmaxf(acc[r], 0.0f);
  }
  pw += __shfl_xor(pw, 32, 64);
  if (lane < 32) partial[wv][col] = pw;
  __syncthreads();
  if (wv == 0 && lane < 32) out[b0 + col] = partial[0][col] + partial[1][col];
}

extern "C" void kernel_launch(void* const* d_in, const int* in_sizes, int n_in,
                              void* d_out, int out_size, void* d_ws, size_t ws_size,
                              hipStream_t stream) {
  const float* x   = (const float*)d_in[0];
  const float* Wxh = (const float*)d_in[1];
  const float* Whh = (const float*)d_in[2];
  const float* Why = (const float*)d_in[3];
  float* out = (float*)d_out;
  (void)in_sizes; (void)n_in; (void)out_size; (void)d_ws; (void)ws_size;
  rnn_scan_kernel<<<dim3(RNN_B / 32), dim3(128), 0, stream>>>(x, Wxh, Whh, Why, out);
}

// Round 7
// 190.843 us; speedup vs baseline: 1.0171x; 1.0171x over previous
//
#include <hip/hip_runtime.h>

// RNN scan: h_{t+1} = relu(W_hh @ h_t + x_t * w_x), out = W_hy @ h_T
// B=8192, T=512, H=64.
// Round 7: K-SPLIT across 2 waves (was M-split). Wave wv owns h rows
// [32wv,32wv+32) == its B-operand k-range. Per step, from REGISTER frags:
//   kept tile: C rows [32wv),   k-half wv, C-in = 0          (2 chained MFMA)
//   sent tile: C rows [32pv),   k-half wv, C-in = x*wx[pv..] (2 chained MFMA)
// Chains are independent -> latencies overlap; NO MFMA waits on LDS.
// Exchange: sent f32 partial (16 f32/lane) via LDS; owner adds kept+recv
// (8 v_pk_add), relu-packs its OWN 2 frag words (k-blocks 2wv,2wv+1) which
// feed its own next-step MFMAs directly. Frag publish round-trip eliminated.
// Layouts (verified rounds 1-6):
//   A 32x32x16: row=lane&31, k=8*(lane>>5)+e
//   B: col=lane&31, k=8*(lane>>5)+e
//   C: col=lane&31, row=(reg&3)+8*(reg>>2)+4*(lane>>5)
//   permlane32_swap(X,Y): X'={self X|partner Y}, Y'={partner X|self Y}

typedef __bf16 bf16x8 __attribute__((ext_vector_type(8)));
typedef float f32x16 __attribute__((ext_vector_type(16)));
typedef unsigned int u32x4 __attribute__((ext_vector_type(4)));

#define RNN_B 8192
#define RNN_T 512
#define RNN_H 64

__device__ __forceinline__ unsigned pk2_relu(float a, float b) {
  float ra = fmaxf(a, 0.0f), rb = fmaxf(b, 0.0f);
  unsigned short ua = __builtin_bit_cast(unsigned short, (__bf16)ra);
  unsigned short ub = __builtin_bit_cast(unsigned short, (__bf16)rb);
  return (unsigned)ua | ((unsigned)ub << 16);
}

__global__ __launch_bounds__(128, 1) void rnn_scan_kernel(
    const float* __restrict__ x,
    const float* __restrict__ Wxh,
    const float* __restrict__ Whh,
    const float* __restrict__ Why,
    float* __restrict__ out)
{
  const int tid  = threadIdx.x;
  const int wv   = tid >> 6;      // k-half / owned rows [32wv, 32wv+32)
  const int pv   = 1 - wv;
  const int lane = tid & 63;
  const int col  = lane & 31;
  const int sel  = lane >> 5;
  const int b0   = blockIdx.x * 32;

  // [buf][owner][word][lane]: partial destined for `owner`, from the other wave
  __shared__ float4 xch[2][2][4][64];        // 16 KiB
  __shared__ float partial[2][32];

  // ---- A fragments: k-columns [32wv,32wv+32), split K=32 as 2 MFMA k-blocks
  // kept: rows [32wv..); sent: rows [32pv..)
  bf16x8 Ak[2], As[2];
#pragma unroll
  for (int kk = 0; kk < 2; ++kk) {
    {
      const float* wp = Whh + (32 * wv + col) * RNN_H + 32 * wv + 16 * kk + 8 * sel;
      float4 w0 = *(const float4*)(wp);
      float4 w1 = *(const float4*)(wp + 4);
      bf16x8 f;
      f[0] = (__bf16)w0.x; f[1] = (__bf16)w0.y; f[2] = (__bf16)w0.z; f[3] = (__bf16)w0.w;
      f[4] = (__bf16)w1.x; f[5] = (__bf16)w1.y; f[6] = (__bf16)w1.z; f[7] = (__bf16)w1.w;
      Ak[kk] = f;
    }
    {
      const float* wp = Whh + (32 * pv + col) * RNN_H + 32 * wv + 16 * kk + 8 * sel;
      float4 w0 = *(const float4*)(wp);
      float4 w1 = *(const float4*)(wp + 4);
      bf16x8 f;
      f[0] = (__bf16)w0.x; f[1] = (__bf16)w0.y; f[2] = (__bf16)w0.z; f[3] = (__bf16)w0.w;
      f[4] = (__bf16)w1.x; f[5] = (__bf16)w1.y; f[6] = (__bf16)w1.z; f[7] = (__bf16)w1.w;
      As[kk] = f;
    }
  }

  // ---- w_x for the SENT tile's rows (partner's rows) ----
  f32x16 wxs;
#pragma unroll
  for (int r = 0; r < 16; ++r)
    wxs[r] = Wxh[32 * pv + (r & 3) + 8 * (r >> 2) + 4 * sel];

  const float* xrow = x + (size_t)(b0 + col) * RNN_T;
  float4 xc0 = *(const float4*)(xrow);
  float4 xc1 = *(const float4*)(xrow + 4);

  f32x16 zf = {};
  f32x16 a = zf;                   // owned rows' pre-relu h (full sum)
  u32x4 fr0 = {}, fr1 = {};        // own B-frags: k-blocks 2wv, 2wv+1 (h_0=0)

  for (int tb = 0; tb < RNN_T; tb += 8) {
    const int tn = (tb + 8 < RNN_T) ? tb + 8 : tb;
    float4 xn0 = *(const float4*)(xrow + tn);
    float4 xn1 = *(const float4*)(xrow + tn + 4);
    const float xs[8] = {xc0.x, xc0.y, xc0.z, xc0.w, xc1.x, xc1.y, xc1.z, xc1.w};
#pragma unroll
    for (int j = 0; j < 8; ++j) {
      const float xv = xs[j];
      // two independent depth-2 chains, all operands in registers
      f32x16 sent = wxs * xv;      // partner's x-term folded into sent C-in
      f32x16 kept;
      sent = __builtin_amdgcn_mfma_f32_32x32x16_bf16(As[0], __builtin_bit_cast(bf16x8, fr0), sent, 0, 0, 0);
      kept = __builtin_amdgcn_mfma_f32_32x32x16_bf16(Ak[0], __builtin_bit_cast(bf16x8, fr0), zf,   0, 0, 0);
      sent = __builtin_amdgcn_mfma_f32_32x32x16_bf16(As[1], __builtin_bit_cast(bf16x8, fr1), sent, 0, 0, 0);
      kept = __builtin_amdgcn_mfma_f32_32x32x16_bf16(Ak[1], __builtin_bit_cast(bf16x8, fr1), kept, 0, 0, 0);

      // ship sent partial to partner (owner = pv)
      const int p = j & 1;
#pragma unroll
      for (int w = 0; w < 4; ++w) {
        float4 v;
        v.x = sent[4 * w + 0]; v.y = sent[4 * w + 1];
        v.z = sent[4 * w + 2]; v.w = sent[4 * w + 3];
        xch[p][pv][w][lane] = v;
      }
      asm volatile("s_waitcnt lgkmcnt(0)\n\ts_barrier" ::: "memory");
      f32x16 recv;
#pragma unroll
      for (int w = 0; w < 4; ++w) {
        float4 v = xch[p][wv][w][lane];
        recv[4 * w + 0] = v.x; recv[4 * w + 1] = v.y;
        recv[4 * w + 2] = v.z; recv[4 * w + 3] = v.w;
      }
      a = kept + recv;             // v_pk_add_f32 x8 (includes own x-term)

      // pack owned rows -> own frag words (k-blocks 2wv, 2wv+1)
      {
        unsigned X0 = pk2_relu(a[0], a[1]);
        unsigned X1 = pk2_relu(a[2], a[3]);
        unsigned Y0 = pk2_relu(a[4], a[5]);
        unsigned Y1 = pk2_relu(a[6], a[7]);
        asm("v_permlane32_swap_b32 %0, %1" : "+v"(X0), "+v"(Y0));
        asm("v_permlane32_swap_b32 %0, %1" : "+v"(X1), "+v"(Y1));
        fr0[0] = X0; fr0[1] = X1; fr0[2] = Y0; fr0[3] = Y1;
      }
      {
        unsigned X0 = pk2_relu(a[8],  a[9]);
        unsigned X1 = pk2_relu(a[10], a[11]);
        unsigned Y0 = pk2_relu(a[12], a[13]);
        unsigned Y1 = pk2_relu(a[14], a[15]);
        asm("v_permlane32_swap_b32 %0, %1" : "+v"(X0), "+v"(Y0));
        asm("v_permlane32_swap_b32 %0, %1" : "+v"(X1), "+v"(Y1));
        fr1[0] = X0; fr1[1] = X1; fr1[2] = Y0; fr1[3] = Y1;
      }
    }
    xc0 = xn0; xc1 = xn1;
  }

  // ---- epilogue: out[b] = sum over owned rows, then cross-wave ----
  float pw = 0.0f;
#pragma unroll
  for (int r = 0; r < 16; ++r) {
    const int row = 32 * wv + (r & 3) + 8 * (r >> 2) + 4 * sel;
    pw += Why[row] * fmaxf(a[r], 0.0f);
  }
  pw += __shfl_xor(pw, 32, 64);
  if (lane < 32) partial[wv][col] = pw;
  __syncthreads();
  if (wv == 0 && lane < 32) out[b0 + col] = partial[0][col] + partial[1][col];
}

extern "C" void kernel_launch(void* const* d_in, const int* in_sizes, int n_in,
                              void* d_out, int out_size, void* d_ws, size_t ws_size,
                              hipStream_t stream) {
  const float* x   = (const float*)d_in[0];
  const float* Wxh = (const float*)d_in[1];
  const float* Whh = (const float*)d_in[2];
  const float* Why = (const float*)d_in[3];
  float* out = (float*)d_out;
  (void)in_sizes; (void)n_in; (void)out_size; (void)d_ws; (void)ws_size;
  rnn_scan_kernel<<<dim3(RNN_B / 32), dim3(128), 0, stream>>>(x, Wxh, Whh, Why, out);
}

// Round 8
// 131.828 us; speedup vs baseline: 1.4725x; 1.4477x over previous
//
#include <hip/hip_runtime.h>

// RNN scan: h_{t+1} = relu(W_hh @ h_t + x_t * w_x), out = W_hy @ h_T
// B=8192, T=512, H=64.
// Round 8 = round-5 skeleton (empirical best, 848 cyc/step) with its two
// exposed latency blocks cut:
//   - own-frag bypass, own-first depth-4 chain: own0/own1 stay in regs; the
//     2 partner words are read at prev step bottom, latency hidden under the
//     two own-MFMAs. (Differs from r6: NO chain split, NO merge adds.)
//   - hardware pack: v_cvt_pk_bf16_f32 x8 + relu-after-pack via
//     v_pk_max_i16(x,0) x8 (neg bf16 is int16-neg; -0 -> +0) + 4 permlane.
//     ~40 cyc vs ~90 for the scalar pk2_relu path.
//   - exchange: write 2xb128, drain covers only those, read 2xb128.
// Layouts (verified rounds 1-7):
//   A 32x32x16: row=lane&31, k=8*(lane>>5)+e
//   B: col=lane&31, k=8*(lane>>5)+e
//   C: col=lane&31, row=(reg&3)+8*(reg>>2)+4*(lane>>5)
//   permlane32_swap(X,Y): X'={self X|partner Y}, Y'={partner X|self Y}

typedef __bf16 bf16x8 __attribute__((ext_vector_type(8)));
typedef float f32x16 __attribute__((ext_vector_type(16)));
typedef unsigned int u32x4 __attribute__((ext_vector_type(4)));

#define RNN_B 8192
#define RNN_T 512
#define RNN_H 64

__global__ __launch_bounds__(128, 1) void rnn_scan_kernel(
    const float* __restrict__ x,
    const float* __restrict__ Wxh,
    const float* __restrict__ Whh,
    const float* __restrict__ Why,
    float* __restrict__ out)
{
  const int tid  = threadIdx.x;
  const int wv   = tid >> 6;      // owns C rows == k-range [32wv, 32wv+32)
  const int pv   = 1 - wv;
  const int lane = tid & 63;
  const int col  = lane & 31;
  const int sel  = lane >> 5;
  const int b0   = blockIdx.x * 32;

  // [buf][srcwave][word][lane]; srcwave w word u = frag k-block 2w+u
  __shared__ u32x4 xch[2][2][2][64];          // 8 KiB
  __shared__ float partial[2][32];

  // ---- A fragments: this wave's 32 rows of W_hh, all 4 k-blocks ----
  bf16x8 A[4];
#pragma unroll
  for (int m = 0; m < 4; ++m) {
    const float* wp = Whh + (32 * wv + col) * RNN_H + 16 * m + 8 * sel;
    float4 w0 = *(const float4*)(wp);
    float4 w1 = *(const float4*)(wp + 4);
    bf16x8 f;
    f[0] = (__bf16)w0.x; f[1] = (__bf16)w0.y; f[2] = (__bf16)w0.z; f[3] = (__bf16)w0.w;
    f[4] = (__bf16)w1.x; f[5] = (__bf16)w1.y; f[6] = (__bf16)w1.z; f[7] = (__bf16)w1.w;
    A[m] = f;
  }

  // ---- w_x per accumulator slot (this wave's rows) ----
  f32x16 wxv;
#pragma unroll
  for (int r = 0; r < 16; ++r)
    wxv[r] = Wxh[32 * wv + (r & 3) + 8 * (r >> 2) + 4 * sel];

  const float* xrow = x + (size_t)(b0 + col) * RNN_T;
  float4 xc0 = *(const float4*)(xrow);
  float4 xc1 = *(const float4*)(xrow + 4);

  f32x16 acc = {};                 // own rows' pre-relu h
  u32x4 own0 = {}, own1 = {};      // own packed frags (k-blocks 2wv, 2wv+1)
  u32x4 p0, p1;                    // partner frags (k-blocks 2pv, 2pv+1)
  unsigned zero_u = 0;

  // prologue: publish h_0 = 0 into buf 0, fetch partner h_0
  xch[0][wv][0][lane] = own0;
  xch[0][wv][1][lane] = own1;
  asm volatile("s_waitcnt lgkmcnt(0)\n\ts_barrier" ::: "memory");
  p0 = xch[0][pv][0][lane];
  p1 = xch[0][pv][1][lane];

  for (int tb = 0; tb < RNN_T; tb += 8) {
    const int tn = (tb + 8 < RNN_T) ? tb + 8 : tb;
    float4 xn0 = *(const float4*)(xrow + tn);
    float4 xn1 = *(const float4*)(xrow + tn + 4);
    const float xs[8] = {xc0.x, xc0.y, xc0.z, xc0.w, xc1.x, xc1.y, xc1.z, xc1.w};
#pragma unroll
    for (int j = 0; j < 8; ++j) {
      const float xv = xs[j];
      // single depth-4 chain, own k-blocks first (register frags -> no wait;
      // p0/p1 lgkm wait lands before MFMA 3, hidden under MFMAs 1-2)
      acc = wxv * xv;              // f32-exact x-term (v_pk_mul)
      acc = __builtin_amdgcn_mfma_f32_32x32x16_bf16(A[2 * wv],     __builtin_bit_cast(bf16x8, own0), acc, 0, 0, 0);
      acc = __builtin_amdgcn_mfma_f32_32x32x16_bf16(A[2 * wv + 1], __builtin_bit_cast(bf16x8, own1), acc, 0, 0, 0);
      acc = __builtin_amdgcn_mfma_f32_32x32x16_bf16(A[2 * pv],     __builtin_bit_cast(bf16x8, p0),   acc, 0, 0, 0);
      acc = __builtin_amdgcn_mfma_f32_32x32x16_bf16(A[2 * pv + 1], __builtin_bit_cast(bf16x8, p1),   acc, 0, 0, 0);

      // pack own rows -> 2 frag words: cvt_pk (RNE), relu on packed bf16,
      // permlane to B-frag lane layout
      unsigned X0, X1, Y0, Y1, X2, X3, Y2, Y3;
      asm("v_cvt_pk_bf16_f32 %0, %1, %2" : "=v"(X0) : "v"(acc[0]),  "v"(acc[1]));
      asm("v_cvt_pk_bf16_f32 %0, %1, %2" : "=v"(X1) : "v"(acc[2]),  "v"(acc[3]));
      asm("v_cvt_pk_bf16_f32 %0, %1, %2" : "=v"(Y0) : "v"(acc[4]),  "v"(acc[5]));
      asm("v_cvt_pk_bf16_f32 %0, %1, %2" : "=v"(Y1) : "v"(acc[6]),  "v"(acc[7]));
      asm("v_cvt_pk_bf16_f32 %0, %1, %2" : "=v"(X2) : "v"(acc[8]),  "v"(acc[9]));
      asm("v_cvt_pk_bf16_f32 %0, %1, %2" : "=v"(X3) : "v"(acc[10]), "v"(acc[11]));
      asm("v_cvt_pk_bf16_f32 %0, %1, %2" : "=v"(Y2) : "v"(acc[12]), "v"(acc[13]));
      asm("v_cvt_pk_bf16_f32 %0, %1, %2" : "=v"(Y3) : "v"(acc[14]), "v"(acc[15]));
      asm("v_pk_max_i16 %0, %1, %2" : "=v"(X0) : "v"(X0), "v"(zero_u));
      asm("v_pk_max_i16 %0, %1, %2" : "=v"(X1) : "v"(X1), "v"(zero_u));
      asm("v_pk_max_i16 %0, %1, %2" : "=v"(Y0) : "v"(Y0), "v"(zero_u));
      asm("v_pk_max_i16 %0, %1, %2" : "=v"(Y1) : "v"(Y1), "v"(zero_u));
      asm("v_pk_max_i16 %0, %1, %2" : "=v"(X2) : "v"(X2), "v"(zero_u));
      asm("v_pk_max_i16 %0, %1, %2" : "=v"(X3) : "v"(X3), "v"(zero_u));
      asm("v_pk_max_i16 %0, %1, %2" : "=v"(Y2) : "v"(Y2), "v"(zero_u));
      asm("v_pk_max_i16 %0, %1, %2" : "=v"(Y3) : "v"(Y3), "v"(zero_u));
      asm("v_permlane32_swap_b32 %0, %1" : "+v"(X0), "+v"(Y0));
      asm("v_permlane32_swap_b32 %0, %1" : "+v"(X1), "+v"(Y1));
      asm("v_permlane32_swap_b32 %0, %1" : "+v"(X2), "+v"(Y2));
      asm("v_permlane32_swap_b32 %0, %1" : "+v"(X3), "+v"(Y3));
      own0[0] = X0; own0[1] = X1; own0[2] = Y0; own0[3] = Y1;
      own1[0] = X2; own1[1] = X3; own1[2] = Y2; own1[3] = Y3;

      // publish h_{t+1} into buf (t+1)&1; fetch partner words for next step
      const int q = (j & 1) ^ 1;
      xch[q][wv][0][lane] = own0;
      xch[q][wv][1][lane] = own1;
      asm volatile("s_waitcnt lgkmcnt(0)\n\ts_barrier" ::: "memory");
      p0 = xch[q][pv][0][lane];
      p1 = xch[q][pv][1][lane];
    }
    xc0 = xn0; xc1 = xn1;
  }

  // ---- epilogue: out[b] = sum over own rows, then cross-wave ----
  float pw = 0.0f;
#pragma unroll
  for (int r = 0; r < 16; ++r) {
    const int row = 32 * wv + (r & 3) + 8 * (r >> 2) + 4 * sel;
    pw += Why[row] * fmaxf(acc[r], 0.0f);
  }
  pw += __shfl_xor(pw, 32, 64);
  if (lane < 32) partial[wv][col] = pw;
  __syncthreads();
  if (wv == 0 && lane < 32) out[b0 + col] = partial[0][col] + partial[1][col];
}

extern "C" void kernel_launch(void* const* d_in, const int* in_sizes, int n_in,
                              void* d_out, int out_size, void* d_ws, size_t ws_size,
                              hipStream_t stream) {
  const float* x   = (const float*)d_in[0];
  const float* Wxh = (const float*)d_in[1];
  const float* Whh = (const float*)d_in[2];
  const float* Why = (const float*)d_in[3];
  float* out = (float*)d_out;
  (void)in_sizes; (void)n_in; (void)out_size; (void)d_ws; (void)ws_size;
  rnn_scan_kernel<<<dim3(RNN_B / 32), dim3(128), 0, stream>>>(x, Wxh, Whh, Why, out);
}